// Round 4
// baseline (277.615 us; speedup 1.0000x reference)
//
#include <hip/hip_runtime.h>

typedef __bf16 bf16_t;
typedef __bf16 bf16x4 __attribute__((ext_vector_type(4)));
typedef __bf16 bf16x8 __attribute__((ext_vector_type(8)));
typedef float floatx4 __attribute__((ext_vector_type(4)));

#define G_GRAPHS 64
#define N_NODES 2000
#define N_EDGES 64000
#define BATCH 10000
#define TED_ 512
#define NOISE_ 128
#define PACDIM_ 6400
#define D0_ 1024
#define D1_ 512
#define MROWS 1000   // BATCH / PAC
#define ESPLIT 8
#define EPB (N_EDGES / ESPLIT)   // 8000 edges per block
#define S0 10         // split-K for layer 0 (640 blocks = 2.5/CU)
#define S1 8          // split-K for layer 1

// prep mega-kernel block ranges
#define PACK_BLKS 5000
#define META_BLKS 2500
#define TW0_BLKS  6400   // (D0/32) * (PACDIM/32) = 32*200
#define TW1_BLKS  512    // (D1/32) * (D0/32)     = 16*32

// ---------------- async global->LDS helper (16B per lane) ----------------
__device__ __forceinline__ void glds16(const void* g, void* l) {
    __builtin_amdgcn_global_load_lds(
        (__attribute__((address_space(1))) void*)(g),
        (__attribute__((address_space(3))) void*)(l), 16, 0, 0);
}

// ------------- kernel 0: zero gnoise+degs+outs (contiguous region) -------------
__global__ __launch_bounds__(256) void zero_kernel(float4* __restrict__ p, int n4) {
    int i = blockIdx.x * 256 + threadIdx.x;
    if (i < n4) p[i] = make_float4(0.f, 0.f, 0.f, 0.f);
}

// ---------- kernel 1a: degree histogram, split over edges ----------
__global__ __launch_bounds__(512) void deg_kernel(
    const int* __restrict__ edge_index, float* __restrict__ degs)
{
    __shared__ float h[N_NODES];
    const int g = blockIdx.y, s = blockIdx.x, tid = threadIdx.x;
    for (int n = tid; n < N_NODES; n += 512) h[n] = 0.f;
    __syncthreads();
    const int* dst = edge_index + (size_t)g * 2 * N_EDGES + N_EDGES + s * EPB;
    for (int e = tid; e < EPB; e += 512) atomicAdd(&h[dst[e]], 1.0f);
    __syncthreads();
    float* dg = degs + (size_t)g * N_NODES;
    for (int n = tid; n < N_NODES; n += 512) {
        float v = h[n];
        if (v != 0.f) atomicAdd(&dg[n], v);
    }
}

// ---------- kernel 1b: message pass, split over edges ----------
__global__ __launch_bounds__(512) void msg_kernel(
    const float* __restrict__ graphs_x, const int* __restrict__ edge_index,
    const float* __restrict__ degs, float* __restrict__ outs)
{
    __shared__ float xsl[N_NODES];
    __shared__ float dvl[N_NODES];
    __shared__ float oh[N_NODES];
    const int g = blockIdx.y, s = blockIdx.x, tid = threadIdx.x;
    const float* xg = graphs_x + (size_t)g * N_NODES;
    const float* dgg = degs + (size_t)g * N_NODES;
    for (int n = tid; n < N_NODES; n += 512) {
        xsl[n] = xg[n];
        dvl[n] = rsqrtf(dgg[n] + 1.0f);   // +1 self-loop
        oh[n] = 0.f;
    }
    __syncthreads();
    const int* src = edge_index + (size_t)g * 2 * N_EDGES + s * EPB;
    const int* dst = src + N_EDGES;
    for (int e = tid; e < EPB; e += 512) {
        int ss = src[e], dd = dst[e];
        atomicAdd(&oh[dd], xsl[ss] * dvl[ss] * dvl[dd]);
    }
    __syncthreads();
    float* og = outs + (size_t)g * N_NODES;
    for (int n = tid; n < N_NODES; n += 512) {
        float v = oh[n];
        if (v != 0.f) atomicAdd(&og[n], v);
    }
}

// ---------- kernel 1c: finish gcn + gnoise[G,128] GEMV, split 4x over nodes ----------
__global__ __launch_bounds__(512) void gnoise_part_kernel(
    const float* __restrict__ graphs_x, const float* __restrict__ degs,
    const float* __restrict__ outs,
    const float* __restrict__ gcn_w, const float* __restrict__ gcn_b,
    const float* __restrict__ gme_w, float* __restrict__ gnoise)
{
    __shared__ float of[500];
    __shared__ float part[4][128];
    const int s = blockIdx.x, g = blockIdx.y, tid = threadIdx.x;
    const int nBase = s * 500;
    const float w = gcn_w[0], b = gcn_b[0];
    for (int n = tid; n < 500; n += 512) {
        int gn = nBase + n;
        float di2 = 1.0f / (degs[(size_t)g * N_NODES + gn] + 1.0f);
        of[n] = w * (outs[(size_t)g * N_NODES + gn]
                     + graphs_x[(size_t)g * N_NODES + gn] * di2) + b;
    }
    __syncthreads();
    const int j = tid & 127, ch = tid >> 7;
    float acc = 0.f;
    const int n0 = ch * 125;
    for (int n = n0; n < n0 + 125; n++)
        acc += of[n] * gme_w[(size_t)(nBase + n) * 128 + j];
    part[ch][j] = acc;
    __syncthreads();
    if (tid < 128)
        atomicAdd(&gnoise[(size_t)g * 128 + tid],
                  part[0][tid] + part[1][tid] + part[2][tid] + part[3][tid]);
}

// ------- kernel 2 (mega-prep): pack | meta-noise | transpose W0 | transpose W1 -------
__global__ __launch_bounds__(256) void prep_kernel(
    const float* __restrict__ in,
    const float* __restrict__ chain, const float* __restrict__ metadata,
    const int* __restrict__ graph_ids,
    const float* __restrict__ meta_w, const float* __restrict__ meta_b,
    const float* __restrict__ gme_w, const float* __restrict__ gme_b,
    const float* __restrict__ gnoise, bf16_t* __restrict__ A,
    const float* __restrict__ seq_w0, bf16_t* __restrict__ W0t,
    const float* __restrict__ seq_w1, bf16_t* __restrict__ W1t)
{
    __shared__ float t[32][33];
    const int blk = blockIdx.x;
    if (blk < PACK_BLKS) {
        // pack input_ fp32 -> A bf16
        int idx = blk * 256 + threadIdx.x;              // over BATCH*512/4
        float4 v = ((const float4*)in)[idx];
        int b = idx >> 7;
        int c = (idx & 127) << 2;
        int r = b / 10, slot = b - r * 10;
        bf16x4 o = { (bf16_t)v.x, (bf16_t)v.y, (bf16_t)v.z, (bf16_t)v.w };
        *(bf16x4*)(A + (size_t)r * PACDIM_ + slot * 640 + c) = o;
        return;
    }
    if (blk < PACK_BLKS + META_BLKS) {
        // meta_emb + noise -> A noise columns (one wave per batch row)
        int wid = ((blk - PACK_BLKS) * 256 + threadIdx.x) >> 6;
        int lane = threadIdx.x & 63;
        const int b = wid;
        float me = 0.f;
        if (lane < 32) {
            me = meta_b[lane] + chain[b] * meta_w[lane];
            for (int i = 1; i < 16; i++)
                me += metadata[(size_t)b * 15 + (i - 1)] * meta_w[(size_t)i * 32 + lane];
            me = me > 0.f ? me : 0.f;
        }
        const int gid = graph_ids[b];
        const int j1 = lane, j2 = lane + 64;
        float n1 = gnoise[(size_t)gid * 128 + j1] + gme_b[j1];
        float n2 = gnoise[(size_t)gid * 128 + j2] + gme_b[j2];
        for (int k = 0; k < 32; k++) {
            float mk = __shfl(me, k, 64);
            const float* wrow = gme_w + (size_t)(N_NODES + k) * 128;
            n1 += mk * wrow[j1];
            n2 += mk * wrow[j2];
        }
        int r = b / 10, slot = b - r * 10;
        bf16_t* dp = A + (size_t)r * PACDIM_ + slot * 640 + TED_;
        dp[j1] = (bf16_t)n1;
        dp[j2] = (bf16_t)n2;
        return;
    }
    // transpose paths
    const float* W; bf16_t* Wt; int R, C, c0, r0;
    if (blk < PACK_BLKS + META_BLKS + TW0_BLKS) {
        int local = blk - PACK_BLKS - META_BLKS;        // [0, 6400)
        W = seq_w0; Wt = W0t; R = PACDIM_; C = D0_;
        c0 = (local & 31) * 32; r0 = (local >> 5) * 32;
    } else {
        int local = blk - PACK_BLKS - META_BLKS - TW0_BLKS;  // [0, 512)
        W = seq_w1; Wt = W1t; R = D0_; C = D1_;
        c0 = (local & 15) * 32; r0 = (local >> 4) * 32;
    }
    int tx = threadIdx.x & 31, ty = threadIdx.x >> 5;
    for (int yy = ty; yy < 32; yy += 8)
        t[yy][tx] = W[(size_t)(r0 + yy) * C + c0 + tx];
    __syncthreads();
    for (int yy = ty; yy < 32; yy += 8)
        Wt[(size_t)(c0 + yy) * R + r0 + tx] = (bf16_t)t[tx][yy];
}

// -------- kernel 5: split-K GEMM partial: P[z] = A[M,Kslice] @ Bt^T --------
// BM=BN=128, BK=32, 256 thr = 4 waves; blockIdx.z = K-split index
__global__ __launch_bounds__(256) void gemm_bt_splitk_kernel(
    const bf16_t* __restrict__ A,   // [M,K] row-major
    const bf16_t* __restrict__ Bt,  // [N,K] row-major
    float* __restrict__ P,          // [S, Mp, N] fp32 partials
    int M, int N, int K, int KS)    // KS = K slice per split
{
    __shared__ __align__(16) bf16_t As[128 * 32];
    __shared__ __align__(16) bf16_t Bs[128 * 32];
    const int tid = threadIdx.x;
    const int wave = tid >> 6;
    const int lane = tid & 63;
    const int mBase = blockIdx.y * 128;
    const int nBase = blockIdx.x * 128;
    const int z = blockIdx.z;
    const int Mp = gridDim.y * 128;
    const int wm = (wave & 1) * 64;
    const int wn = (wave >> 1) * 64;

    floatx4 acc[4][4] = {};

    const int c0 = tid, c1 = tid + 256;
    const int rA0 = c0 >> 2, k80 = (c0 & 3) * 8;
    const int rA1 = c1 >> 2, k81 = (c1 & 3) * 8;
    int gm0 = mBase + rA0; if (gm0 > M - 1) gm0 = M - 1;
    int gm1 = mBase + rA1; if (gm1 > M - 1) gm1 = M - 1;
    const bf16_t* aP0 = A + (size_t)gm0 * K + k80;
    const bf16_t* aP1 = A + (size_t)gm1 * K + k81;
    const bf16_t* bP0 = Bt + (size_t)(nBase + rA0) * K + k80;
    const bf16_t* bP1 = Bt + (size_t)(nBase + rA1) * K + k81;
    char* lA0 = (char*)As + wave * 1024;
    char* lA1 = (char*)As + 4096 + wave * 1024;
    char* lB0 = (char*)Bs + wave * 1024;
    char* lB1 = (char*)Bs + 4096 + wave * 1024;

    const int kq = (lane >> 4) * 8;
    const int mr = lane & 15;
    const bf16x8* ra[4]; const bf16x8* rb[4];
    for (int i = 0; i < 4; i++)
        ra[i] = (const bf16x8*)&As[(wm + i * 16 + mr) * 32 + kq];
    for (int j = 0; j < 4; j++)
        rb[j] = (const bf16x8*)&Bs[(wn + j * 16 + mr) * 32 + kq];

    const int kEnd = z * KS + KS;
    for (int k0 = z * KS; k0 < kEnd; k0 += 32) {
        __syncthreads();
        glds16(aP0 + k0, lA0);
        glds16(aP1 + k0, lA1);
        glds16(bP0 + k0, lB0);
        glds16(bP1 + k0, lB1);
        __syncthreads();
        bf16x8 af[4], bfr[4];
        for (int i = 0; i < 4; i++) af[i] = *ra[i];
        for (int j = 0; j < 4; j++) bfr[j] = *rb[j];
        for (int i = 0; i < 4; i++)
            for (int j = 0; j < 4; j++)
                acc[i][j] = __builtin_amdgcn_mfma_f32_16x16x32_bf16(
                    af[i], bfr[j], acc[i][j], 0, 0, 0);
    }

    float* Pz = P + (size_t)z * Mp * N;
    const int rq = (lane >> 4) * 4;
    const int cn = lane & 15;
    for (int j = 0; j < 4; j++) {
        int col = nBase + wn + j * 16 + cn;
        for (int i = 0; i < 4; i++)
            for (int r = 0; r < 4; r++) {
                int rowm = mBase + wm + i * 16 + rq + r;
                Pz[(size_t)rowm * N + col] = acc[i][j][r];
            }
    }
}

// -------- kernel 5b: reduce split-K partials + bias + leaky -> bf16 --------
__global__ __launch_bounds__(256) void reduce_bias_leaky_kernel(
    const float* __restrict__ P, const float* __restrict__ bias,
    bf16_t* __restrict__ C, int M, int N, int Mp, int S)
{
    int idx = blockIdx.x * 256 + threadIdx.x;
    int total = M * (N >> 2);
    if (idx >= total) return;
    int nv = N >> 2;
    int r = idx / nv, c4 = (idx - r * nv) << 2;
    size_t off = (size_t)r * N + c4;
    size_t stride = (size_t)Mp * N;
    float4 v = *(const float4*)(P + off);
    for (int s = 1; s < S; s++) {
        float4 u = *(const float4*)(P + s * stride + off);
        v.x += u.x; v.y += u.y; v.z += u.z; v.w += u.w;
    }
    const float4 bv = *(const float4*)(bias + c4);
    v.x += bv.x; v.y += bv.y; v.z += bv.z; v.w += bv.w;
    v.x = v.x > 0.f ? v.x : 0.2f * v.x;
    v.y = v.y > 0.f ? v.y : 0.2f * v.y;
    v.z = v.z > 0.f ? v.z : 0.2f * v.z;
    v.w = v.w > 0.f ? v.w : 0.2f * v.w;
    bf16x4 o = { (bf16_t)v.x, (bf16_t)v.y, (bf16_t)v.z, (bf16_t)v.w };
    *(bf16x4*)(C + off) = o;
}

// ---- kernel 6: fused reduce(P1) + bias + leaky + dot(w2) + b2 -> out[r] ----
__global__ __launch_bounds__(256) void final_fused_kernel(
    const float* __restrict__ P, const float* __restrict__ b1,
    const float* __restrict__ w2, const float* __restrict__ b2,
    float* __restrict__ out, int Mp, int S)
{
    int wid = (blockIdx.x * 256 + threadIdx.x) >> 6;
    int lane = threadIdx.x & 63;
    if (wid >= MROWS) return;
    size_t stride = (size_t)Mp * D1_;
    const float* base = P + (size_t)wid * D1_;
    float s = 0.f;
    for (int i = 0; i < 8; i++) {
        int c = i * 64 + lane;
        float v = base[c];
        for (int z = 1; z < S; z++) v += base[(size_t)z * stride + c];
        v += b1[c];
        v = v > 0.f ? v : 0.2f * v;
        s += v * w2[c];
    }
    for (int off = 32; off; off >>= 1) s += __shfl_down(s, off, 64);
    if (lane == 0) out[wid] = s + b2[0];
}

// ---------------------------- launcher ----------------------------
extern "C" void kernel_launch(void* const* d_in, const int* in_sizes, int n_in,
                              void* d_out, int out_size, void* d_ws, size_t ws_size,
                              hipStream_t stream)
{
    const float* input_    = (const float*)d_in[0];
    const float* graphs_x  = (const float*)d_in[1];
    const int*   edge_idx  = (const int*)  d_in[2];
    const int*   graph_ids = (const int*)  d_in[3];
    const float* chain     = (const float*)d_in[4];
    const float* metadata  = (const float*)d_in[5];
    const float* gcn_w     = (const float*)d_in[6];
    const float* gcn_b     = (const float*)d_in[7];
    const float* meta_w    = (const float*)d_in[8];
    const float* meta_b    = (const float*)d_in[9];
    const float* gme_w     = (const float*)d_in[10];
    const float* gme_b     = (const float*)d_in[11];
    const float* seq_w0    = (const float*)d_in[12];
    const float* seq_b0    = (const float*)d_in[13];
    const float* seq_w1    = (const float*)d_in[14];
    const float* seq_b1    = (const float*)d_in[15];
    const float* seq_w2    = (const float*)d_in[16];
    const float* seq_b2    = (const float*)d_in[17];
    float* out = (float*)d_out;

    char* ws = (char*)d_ws;
    // workspace layout (gnoise|degs|outs contiguous for one-shot zeroing)
    float*  gnoise = (float*)(ws + 0);              //  64*128*4    =    32768
    float*  degs   = (float*)(ws + 32768);          //  64*2000*4   =   512000
    float*  outs   = (float*)(ws + 544768);         //  64*2000*4   =   512000
    bf16_t* Abuf   = (bf16_t*)(ws + 1056768);       // 1000*6400*2  = 12800000
    bf16_t* W0t    = (bf16_t*)(ws + 13856768);      // 1024*6400*2  = 13107200
    bf16_t* W1t    = (bf16_t*)(ws + 26963968);      //  512*1024*2  =  1048576
    bf16_t* H1     = (bf16_t*)(ws + 28012544);      // 1000*1024*2  =  2048000
    float*  P      = (float*)(ws + 30060544);       // S0*1024*1024*4 = 41.9 MB
    // total ~72 MB

    const int zn4 = (32768 + 512000 + 512000) / 16;   // 66048 float4
    zero_kernel<<<(zn4 + 255) / 256, 256, 0, stream>>>((float4*)gnoise, zn4);
    deg_kernel<<<dim3(ESPLIT, G_GRAPHS), 512, 0, stream>>>(edge_idx, degs);
    msg_kernel<<<dim3(ESPLIT, G_GRAPHS), 512, 0, stream>>>(graphs_x, edge_idx, degs, outs);
    gnoise_part_kernel<<<dim3(4, G_GRAPHS), 512, 0, stream>>>(
        graphs_x, degs, outs, gcn_w, gcn_b, gme_w, gnoise);

    prep_kernel<<<PACK_BLKS + META_BLKS + TW0_BLKS + TW1_BLKS, 256, 0, stream>>>(
        input_, chain, metadata, graph_ids, meta_w, meta_b, gme_w, gme_b,
        gnoise, Abuf, seq_w0, W0t, seq_w1, W1t);

    // layer 0: M=1000 N=1024 K=6400, split-K=10 (KS=640) -> 8x8x10 = 640 blocks
    gemm_bt_splitk_kernel<<<dim3(D0_ / 128, 8, S0), 256, 0, stream>>>(
        Abuf, W0t, P, MROWS, D0_, PACDIM_, PACDIM_ / S0);
    reduce_bias_leaky_kernel<<<(MROWS * D0_ / 4 + 255) / 256, 256, 0, stream>>>(
        P, seq_b0, H1, MROWS, D0_, 1024, S0);

    // layer 1: M=1000 N=512 K=1024, split-K=8 (KS=128) -> 4x8x8 = 256 blocks
    gemm_bt_splitk_kernel<<<dim3(D1_ / 128, 8, S1), 256, 0, stream>>>(
        H1, W1t, P, MROWS, D1_, D0_, D0_ / S1);
    // fused: reduce P1 + bias + leaky + dot w2 + b2 -> out
    final_fused_kernel<<<(MROWS * 64 + 255) / 256, 256, 0, stream>>>(
        P, seq_b1, seq_w2, seq_b2, out, 1024, S1);
}